// Round 6
// baseline (126.496 us; speedup 1.0000x reference)
//
#include <hip/hip_runtime.h>

#define NB 32
#define CC 64
#define CS 32      // score cols: 0..15 alpha(x1), 16..31 phi(x2)
#define TT 300
#define VV 25
#define HH 16
#define TPOUT 150
#define KH 4       // kernel//2
#define TC 4       // timesteps per k1 block

#define TPC 25     // selected rows per k2 chunk
#define NCHUNK 6
#define ROWS_MAX 57
#define SLV 68     // k2 value-band LDS leading dim
#define SLS 36     // k2 score-band LDS leading dim
#define K1LD 100   // k1 LDS leading dim (400B rows, 16B-aligned)

// ---------------- Kernel 0: Ws = [W@alphaT | W@phiT]  (64 x 32) --------------
__global__ __launch_bounds__(256) void k0_ws(const float* __restrict__ W,
                                             const float* __restrict__ alpha,
                                             const float* __restrict__ phi,
                                             float* __restrict__ Ws) {
    __shared__ float sW[64][64];
    __shared__ float sA[32][64];   // rows 0..15 alpha, 16..31 phi
    const int tid = threadIdx.x;
    for (int i = tid; i < 1024; i += 256)
        reinterpret_cast<float4*>(&sW[0][0])[i] = reinterpret_cast<const float4*>(W)[i];
    for (int i = tid; i < 512; i += 256) {
        float4 v = (i < 256) ? reinterpret_cast<const float4*>(alpha)[i]
                             : reinterpret_cast<const float4*>(phi)[i - 256];
        reinterpret_cast<float4*>(&sA[0][0])[i] = v;
    }
    __syncthreads();
    for (int i = tid; i < 2048; i += 256) {
        int ci = i >> 5, j = i & 31;
        const float4* a = reinterpret_cast<const float4*>(&sW[ci][0]);
        const float4* b = reinterpret_cast<const float4*>(&sA[j][0]);
        float acc = 0.f;
#pragma unroll
        for (int q = 0; q < 16; ++q) {
            float4 u = a[q], w = b[q];
            acc += u.x * w.x + u.y * w.y + u.z * w.z + u.w * w.w;
        }
        Ws[(size_t)ci * CS + j] = acc;
    }
}

// ---------------- Kernel 1: xwv/xws = x-slice @ [W | Ws] ---------------------
// 2D register tiling (5 tv x 8 col, 240 threads) + depth-1 register prefetch
// to hide LDS latency (3 blocks/CU -> only 3 waves/SIMD; without prefetch the
// read->FMA chain stalls the VALU at ~37%).
__global__ __launch_bounds__(256) void k1_xw(const float* __restrict__ x,
                                             const float* __restrict__ W,
                                             const float* __restrict__ Ws,
                                             float* __restrict__ xwv,
                                             float* __restrict__ xws) {
    __shared__ float sW[64][K1LD];   // cols 0..63 = W, 64..95 = Ws
    __shared__ float sx[64][K1LD];   // [ci][tv], tv = tloc*25+v, 100 used
    const int n  = blockIdx.y;
    const int t0 = blockIdx.x * TC;
    const int tid = threadIdx.x;

    for (int i = tid; i < 1024; i += 256) {              // W cols 0..63
        int ci = i >> 4, q = i & 15;
        *reinterpret_cast<float4*>(&sW[ci][4 * q]) = reinterpret_cast<const float4*>(W)[i];
    }
    for (int i = tid; i < 512; i += 256) {               // Ws cols 64..95
        int ci = i >> 3, q = i & 7;
        *reinterpret_cast<float4*>(&sW[ci][64 + 4 * q]) = reinterpret_cast<const float4*>(Ws)[i];
    }
    const float* xb = x + (size_t)n * CC * TT * VV + (size_t)t0 * VV;
    for (int i = tid; i < 64 * 25; i += 256) {
        int ci = i / 25, q = i - ci * 25;
        *reinterpret_cast<float4*>(&sx[ci][4 * q]) =
            *reinterpret_cast<const float4*>(&xb[(size_t)ci * TT * VV + 4 * q]);
    }
    __syncthreads();

    if (tid < 240) {
        const int tvg  = tid / 12;        // 12 consecutive lanes share tvg (x broadcast)
        const int colg = tid % 12;
        const int tv0  = tvg * 5;
        const int col0 = colg * 8;        // colg<8 -> value cols, >=8 -> score cols

        float acc[5][8];
#pragma unroll
        for (int i = 0; i < 5; ++i)
#pragma unroll
            for (int j = 0; j < 8; ++j) acc[i][j] = 0.f;

        // prime the software pipeline with ci = 0
        float xr[5];
#pragma unroll
        for (int i = 0; i < 5; ++i) xr[i] = sx[0][tv0 + i];
        float4 w0 = *reinterpret_cast<const float4*>(&sW[0][col0]);
        float4 w1 = *reinterpret_cast<const float4*>(&sW[0][col0 + 4]);

#pragma unroll 2
        for (int ci = 0; ci < 64; ++ci) {
            // prefetch ci+1 (wraps to 0 on last iter; harmless)
            const int cn = (ci + 1) & 63;
            float xn[5];
#pragma unroll
            for (int i = 0; i < 5; ++i) xn[i] = sx[cn][tv0 + i];
            float4 nw0 = *reinterpret_cast<const float4*>(&sW[cn][col0]);
            float4 nw1 = *reinterpret_cast<const float4*>(&sW[cn][col0 + 4]);

#pragma unroll
            for (int i = 0; i < 5; ++i) {
                acc[i][0] = fmaf(xr[i], w0.x, acc[i][0]);
                acc[i][1] = fmaf(xr[i], w0.y, acc[i][1]);
                acc[i][2] = fmaf(xr[i], w0.z, acc[i][2]);
                acc[i][3] = fmaf(xr[i], w0.w, acc[i][3]);
                acc[i][4] = fmaf(xr[i], w1.x, acc[i][4]);
                acc[i][5] = fmaf(xr[i], w1.y, acc[i][5]);
                acc[i][6] = fmaf(xr[i], w1.z, acc[i][6]);
                acc[i][7] = fmaf(xr[i], w1.w, acc[i][7]);
            }

#pragma unroll
            for (int i = 0; i < 5; ++i) xr[i] = xn[i];
            w0 = nw0; w1 = nw1;
        }

#pragma unroll
        for (int i = 0; i < 5; ++i) {
            int tv = tv0 + i;
            int tloc = tv / 25, v = tv - 25 * tloc;
            size_t row = (size_t)(n * VV + v) * TT + (t0 + tloc);
            float4 sA = {acc[i][0], acc[i][1], acc[i][2], acc[i][3]};
            float4 sB = {acc[i][4], acc[i][5], acc[i][6], acc[i][7]};
            if (colg < 8) {
                float* p = &xwv[row * CC + col0];
                *reinterpret_cast<float4*>(p)     = sA;
                *reinterpret_cast<float4*>(p + 4) = sB;
            } else {
                float* p = &xws[row * CS + (col0 - 64)];
                *reinterpret_cast<float4*>(p)     = sA;
                *reinterpret_cast<float4*>(p + 4) = sB;
            }
        }
    }
}

// ---------------- Kernel 1b: ssum[r][c] = sum_t xwv[r][t][c] -----------------
__global__ __launch_bounds__(256) void k1b_colsum(const float* __restrict__ xwv,
                                                  float* __restrict__ ssum) {
    __shared__ float sred[16][64];
    const int r = blockIdx.x;
    const float* p = xwv + (size_t)r * TT * CC;
    const int c4 = threadIdx.x & 15, g = threadIdx.x >> 4;
    float4 a = {0.f, 0.f, 0.f, 0.f};
    for (int t = g; t < TT; t += 16) {
        float4 v = *reinterpret_cast<const float4*>(&p[(size_t)t * CC + 4 * c4]);
        a.x += v.x; a.y += v.y; a.z += v.z; a.w += v.w;
    }
    *reinterpret_cast<float4*>(&sred[g][4 * c4]) = a;
    __syncthreads();
    if (threadIdx.x < 64) {
        float acc = 0.f;
#pragma unroll
        for (int g2 = 0; g2 < 16; ++g2) acc += sred[g2][threadIdx.x];
        ssum[(size_t)r * CC + threadIdx.x] = acc;
    }
}

// ---------------- Kernel 2: banded attention, one (chunk, r) per block -------
__global__ __launch_bounds__(256) void k2_attn(const float* __restrict__ xwv,
                                               const float* __restrict__ xws,
                                               const float* __restrict__ ssum,
                                               float* __restrict__ tmp) {
    const int ch = blockIdx.x;    // 0..5
    const int r  = blockIdx.y;    // n*25 + v

    __shared__ __align__(16) float sxv[ROWS_MAX][SLV];  // value cols
    __shared__ __align__(16) float sxs[ROWS_MAX][SLS];  // score cols
    __shared__ float sss[CC];
    __shared__ float sscore[TPC][9];
    __shared__ float scoef[TPC][10];

    const int tid = threadIdx.x;
    const int tp0 = ch * TPC;
    const int s_lo = max(0, 2 * tp0 - KH);
    const int s_hi = min(TT - 1, 2 * (tp0 + TPC - 1) + KH);
    const int rows = s_hi - s_lo + 1;

    const float* bv = xwv + ((size_t)r * TT + s_lo) * CC;
    for (int i = tid; i < rows * 16; i += 256) {
        int row = i >> 4, q = i & 15;
        *reinterpret_cast<float4*>(&sxv[row][4 * q]) =
            *reinterpret_cast<const float4*>(&bv[(size_t)row * CC + 4 * q]);
    }
    const float* bs = xws + ((size_t)r * TT + s_lo) * CS;
    for (int i = tid; i < rows * 8; i += 256) {
        int row = i >> 3, q = i & 7;
        *reinterpret_cast<float4*>(&sxs[row][4 * q]) =
            *reinterpret_cast<const float4*>(&bs[(size_t)row * CS + 4 * q]);
    }
    if (tid < CC) sss[tid] = ssum[(size_t)r * CC + tid];
    __syncthreads();

    // band scores: x1 = sxs[t][0..15], x2 = sxs[s][16..31]
    if (tid < TPC * 9) {
        int tpl = tid / 9, k = tid - tpl * 9;
        int t = 2 * (tp0 + tpl);
        int s = t - KH + k;
        float sc = 0.f;
        if (s >= 0 && s < TT) {
            const float4* x1 = reinterpret_cast<const float4*>(&sxs[t - s_lo][0]);
            const float4* x2 = reinterpret_cast<const float4*>(&sxs[s - s_lo][16]);
#pragma unroll
            for (int q = 0; q < 4; ++q) {
                float4 a = x1[q], b = x2[q];
                sc += a.x * b.x + a.y * b.y + a.z * b.z + a.w * b.w;
            }
        }
        sscore[tpl][k] = sc;
    }
    __syncthreads();

    // softmax coefficients (out-of-band zeros fold analytically)
    if (tid < TPC) {
        int tpl = tid;
        int t = 2 * (tp0 + tpl);
        float m = 0.f;
        int nb = 0;
#pragma unroll
        for (int k = 0; k < 9; ++k) {
            int s = t - KH + k;
            if (s >= 0 && s < TT) { nb++; m = fmaxf(m, sscore[tpl][k]); }
        }
        float wbg = __expf(-m);
        float Z = (float)(TT - nb) * wbg;
        float e[9];
#pragma unroll
        for (int k = 0; k < 9; ++k) {
            int s = t - KH + k;
            float ek = (s >= 0 && s < TT) ? __expf(sscore[tpl][k] - m) : 0.f;
            e[k] = ek;
            Z += ek;
        }
        float inv = 1.f / Z;
#pragma unroll
        for (int k = 0; k < 9; ++k) {
            int s = t - KH + k;
            scoef[tpl][k] = (s >= 0 && s < TT) ? (e[k] - wbg) * inv : 0.f;
        }
        scoef[tpl][9] = wbg * inv;
    }
    __syncthreads();

    // tmp[r][tp][c] = cbg*ssum[c] + sum_k coef_k * xwv_band[row][c]
    for (int i = tid; i < TPC * CC; i += 256) {
        int tpl = i >> 6, c = i & 63;
        int t = 2 * (tp0 + tpl);
        int row0 = t - KH - s_lo;
        float val = scoef[tpl][9] * sss[c];
#pragma unroll
        for (int k = 0; k < 9; ++k) {
            int row = row0 + k;
            row = min(max(row, 0), rows - 1);   // coef is 0 for invalid slots
            val += scoef[tpl][k] * sxv[row][c];
        }
        tmp[((size_t)r * TPOUT + (tp0 + tpl)) * CC + c] = val;
    }
}

// ---------------- Kernel 3: tmp[n][v][tp][c] -> out[n][c][tp][v] -------------
#define TPT 5
__global__ __launch_bounds__(256) void k3_transpose(const float* __restrict__ tmp,
                                                    float* __restrict__ out) {
    __shared__ float tile[VV][TPT][65];
    const int n = blockIdx.y;
    const int tp0 = blockIdx.x * TPT;
    const int tid = threadIdx.x;

    const float* src = tmp + (size_t)n * (VV * TPOUT * CC);
    for (int i = tid; i < VV * TPT * CC; i += 256) {
        int v = i / (TPT * CC);
        int rem = i - v * (TPT * CC);
        int tpl = rem >> 6, c = rem & 63;
        tile[v][tpl][c] = src[((size_t)v * TPOUT + tp0 + tpl) * CC + c];
    }
    __syncthreads();
    float* dst = out + (size_t)n * (CC * TPOUT * VV);
    for (int j = tid; j < CC * TPT * VV; j += 256) {
        int c = j / (TPT * VV);
        int rem = j - c * (TPT * VV);
        int tpl = rem / VV, v = rem - tpl * VV;
        dst[(size_t)c * (TPOUT * VV) + (tp0 + tpl) * VV + v] = tile[v][tpl][c];
    }
}

extern "C" void kernel_launch(void* const* d_in, const int* in_sizes, int n_in,
                              void* d_out, int out_size, void* d_ws, size_t ws_size,
                              hipStream_t stream) {
    const float* x     = (const float*)d_in[0];
    const float* W     = (const float*)d_in[1];
    const float* alpha = (const float*)d_in[2];
    const float* phi   = (const float*)d_in[3];
    float* out = (float*)d_out;

    float* xwv  = (float*)d_ws;                         // 800*300*64 = 15,360,000 f
    float* xws  = xwv + (size_t)800 * 300 * CC;         // 800*300*32 =  7,680,000 f
    float* tmp  = xws + (size_t)800 * 300 * CS;         // 800*150*64 =  7,680,000 f
    float* ssum = tmp + (size_t)800 * 150 * 64;         // 800*64     =     51,200 f
    float* Ws   = ssum + (size_t)800 * 64;              // 64*32      =      2,048 f
                                                        // total ~123 MB

    k0_ws<<<1, 256, 0, stream>>>(W, alpha, phi, Ws);
    dim3 g1(TT / TC, NB);
    k1_xw<<<g1, 256, 0, stream>>>(x, W, Ws, xwv, xws);
    k1b_colsum<<<NB * VV, 256, 0, stream>>>(xwv, ssum);
    dim3 g2(NCHUNK, NB * VV);
    k2_attn<<<g2, 256, 0, stream>>>(xwv, xws, ssum, tmp);
    dim3 g3(TPOUT / TPT, NB);
    k3_transpose<<<g3, 256, 0, stream>>>(tmp, out);
}

// Round 7
// 117.917 us; speedup vs baseline: 1.0728x; 1.0728x over previous
//
#include <hip/hip_runtime.h>

#define NB 32
#define CC 64
#define CS 32      // score cols: 0..15 alpha(x1), 16..31 phi(x2)
#define TT 300
#define VV 25
#define HH 16
#define TPOUT 150
#define KH 4       // kernel//2
#define TC 4       // timesteps per k1 block

#define TPC 25     // selected rows per k2 chunk
#define NCHUNK 6
#define ROWS_MAX 57
#define SLV 68     // k2 value-band LDS leading dim
#define SLS 36     // k2 score-band LDS leading dim
#define K1LD 100   // k1 LDS leading dim (400B rows, 16B-aligned)

// ---------------- Kernel 0: Ws = [W@alphaT | W@phiT]  (64 x 32) --------------
__global__ __launch_bounds__(256) void k0_ws(const float* __restrict__ W,
                                             const float* __restrict__ alpha,
                                             const float* __restrict__ phi,
                                             float* __restrict__ Ws) {
    __shared__ float sW[64][64];
    __shared__ float sA[32][64];   // rows 0..15 alpha, 16..31 phi
    const int tid = threadIdx.x;
    for (int i = tid; i < 1024; i += 256)
        reinterpret_cast<float4*>(&sW[0][0])[i] = reinterpret_cast<const float4*>(W)[i];
    for (int i = tid; i < 512; i += 256) {
        float4 v = (i < 256) ? reinterpret_cast<const float4*>(alpha)[i]
                             : reinterpret_cast<const float4*>(phi)[i - 256];
        reinterpret_cast<float4*>(&sA[0][0])[i] = v;
    }
    __syncthreads();
    for (int i = tid; i < 2048; i += 256) {
        int ci = i >> 5, j = i & 31;
        const float4* a = reinterpret_cast<const float4*>(&sW[ci][0]);
        const float4* b = reinterpret_cast<const float4*>(&sA[j][0]);
        float acc = 0.f;
#pragma unroll
        for (int q = 0; q < 16; ++q) {
            float4 u = a[q], w = b[q];
            acc += u.x * w.x + u.y * w.y + u.z * w.z + u.w * w.w;
        }
        Ws[(size_t)ci * CS + j] = acc;
    }
}

// ---------------- Kernel 1: xwv/xws = x-slice @ [W | Ws] ---------------------
// 2D register tiling (5 tv x 8 col, 240 threads). LDS caps occupancy at
// 3 blocks/CU, so VGPRs up to 168 are free: launch_bounds(256,3) + explicit
// 4-ci read batching (28 ds_reads -> 160 FMAs) to hide LDS latency.
__global__ __launch_bounds__(256, 3) void k1_xw(const float* __restrict__ x,
                                                const float* __restrict__ W,
                                                const float* __restrict__ Ws,
                                                float* __restrict__ xwv,
                                                float* __restrict__ xws) {
    __shared__ float sW[64][K1LD];   // cols 0..63 = W, 64..95 = Ws
    __shared__ float sx[64][K1LD];   // [ci][tv], tv = tloc*25+v, 100 used
    const int n  = blockIdx.y;
    const int t0 = blockIdx.x * TC;
    const int tid = threadIdx.x;

    for (int i = tid; i < 1024; i += 256) {              // W cols 0..63
        int ci = i >> 4, q = i & 15;
        *reinterpret_cast<float4*>(&sW[ci][4 * q]) = reinterpret_cast<const float4*>(W)[i];
    }
    for (int i = tid; i < 512; i += 256) {               // Ws cols 64..95
        int ci = i >> 3, q = i & 7;
        *reinterpret_cast<float4*>(&sW[ci][64 + 4 * q]) = reinterpret_cast<const float4*>(Ws)[i];
    }
    const float* xb = x + (size_t)n * CC * TT * VV + (size_t)t0 * VV;
    for (int i = tid; i < 64 * 25; i += 256) {
        int ci = i / 25, q = i - ci * 25;
        *reinterpret_cast<float4*>(&sx[ci][4 * q]) =
            *reinterpret_cast<const float4*>(&xb[(size_t)ci * TT * VV + 4 * q]);
    }
    __syncthreads();

    if (tid < 240) {
        const int tvg  = tid / 12;        // 12 consecutive lanes share tvg (x broadcast)
        const int colg = tid % 12;
        const int tv0  = tvg * 5;
        const int col0 = colg * 8;        // colg<8 -> value cols, >=8 -> score cols

        float acc[5][8];
#pragma unroll
        for (int i = 0; i < 5; ++i)
#pragma unroll
            for (int j = 0; j < 8; ++j) acc[i][j] = 0.f;

        for (int cb = 0; cb < 64; cb += 4) {
            // burst-load 4 ci's worth of operands (28 ds_reads in flight)
            float  xc[4][5];
            float4 w0c[4], w1c[4];
#pragma unroll
            for (int u = 0; u < 4; ++u) {
#pragma unroll
                for (int i = 0; i < 5; ++i) xc[u][i] = sx[cb + u][tv0 + i];
                w0c[u] = *reinterpret_cast<const float4*>(&sW[cb + u][col0]);
                w1c[u] = *reinterpret_cast<const float4*>(&sW[cb + u][col0 + 4]);
            }
            // 160 FMAs
#pragma unroll
            for (int u = 0; u < 4; ++u) {
#pragma unroll
                for (int i = 0; i < 5; ++i) {
                    acc[i][0] = fmaf(xc[u][i], w0c[u].x, acc[i][0]);
                    acc[i][1] = fmaf(xc[u][i], w0c[u].y, acc[i][1]);
                    acc[i][2] = fmaf(xc[u][i], w0c[u].z, acc[i][2]);
                    acc[i][3] = fmaf(xc[u][i], w0c[u].w, acc[i][3]);
                    acc[i][4] = fmaf(xc[u][i], w1c[u].x, acc[i][4]);
                    acc[i][5] = fmaf(xc[u][i], w1c[u].y, acc[i][5]);
                    acc[i][6] = fmaf(xc[u][i], w1c[u].z, acc[i][6]);
                    acc[i][7] = fmaf(xc[u][i], w1c[u].w, acc[i][7]);
                }
            }
        }

#pragma unroll
        for (int i = 0; i < 5; ++i) {
            int tv = tv0 + i;
            int tloc = tv / 25, v = tv - 25 * tloc;
            size_t row = (size_t)(n * VV + v) * TT + (t0 + tloc);
            float4 sA = {acc[i][0], acc[i][1], acc[i][2], acc[i][3]};
            float4 sB = {acc[i][4], acc[i][5], acc[i][6], acc[i][7]};
            if (colg < 8) {
                float* p = &xwv[row * CC + col0];
                *reinterpret_cast<float4*>(p)     = sA;
                *reinterpret_cast<float4*>(p + 4) = sB;
            } else {
                float* p = &xws[row * CS + (col0 - 64)];
                *reinterpret_cast<float4*>(p)     = sA;
                *reinterpret_cast<float4*>(p + 4) = sB;
            }
        }
    }
}

// ---------------- Kernel 1b: ssum[r][c] = sum_t xwv[r][t][c] -----------------
__global__ __launch_bounds__(256) void k1b_colsum(const float* __restrict__ xwv,
                                                  float* __restrict__ ssum) {
    __shared__ float sred[16][64];
    const int r = blockIdx.x;
    const float* p = xwv + (size_t)r * TT * CC;
    const int c4 = threadIdx.x & 15, g = threadIdx.x >> 4;
    float4 a = {0.f, 0.f, 0.f, 0.f};
    for (int t = g; t < TT; t += 16) {
        float4 v = *reinterpret_cast<const float4*>(&p[(size_t)t * CC + 4 * c4]);
        a.x += v.x; a.y += v.y; a.z += v.z; a.w += v.w;
    }
    *reinterpret_cast<float4*>(&sred[g][4 * c4]) = a;
    __syncthreads();
    if (threadIdx.x < 64) {
        float acc = 0.f;
#pragma unroll
        for (int g2 = 0; g2 < 16; ++g2) acc += sred[g2][threadIdx.x];
        ssum[(size_t)r * CC + threadIdx.x] = acc;
    }
}

// ---------------- Kernel 2: banded attention, one (chunk, r) per block -------
__global__ __launch_bounds__(256) void k2_attn(const float* __restrict__ xwv,
                                               const float* __restrict__ xws,
                                               const float* __restrict__ ssum,
                                               float* __restrict__ tmp) {
    const int ch = blockIdx.x;    // 0..5
    const int r  = blockIdx.y;    // n*25 + v

    __shared__ __align__(16) float sxv[ROWS_MAX][SLV];  // value cols
    __shared__ __align__(16) float sxs[ROWS_MAX][SLS];  // score cols
    __shared__ float sss[CC];
    __shared__ float sscore[TPC][9];
    __shared__ float scoef[TPC][10];

    const int tid = threadIdx.x;
    const int tp0 = ch * TPC;
    const int s_lo = max(0, 2 * tp0 - KH);
    const int s_hi = min(TT - 1, 2 * (tp0 + TPC - 1) + KH);
    const int rows = s_hi - s_lo + 1;

    const float* bv = xwv + ((size_t)r * TT + s_lo) * CC;
    for (int i = tid; i < rows * 16; i += 256) {
        int row = i >> 4, q = i & 15;
        *reinterpret_cast<float4*>(&sxv[row][4 * q]) =
            *reinterpret_cast<const float4*>(&bv[(size_t)row * CC + 4 * q]);
    }
    const float* bs = xws + ((size_t)r * TT + s_lo) * CS;
    for (int i = tid; i < rows * 8; i += 256) {
        int row = i >> 3, q = i & 7;
        *reinterpret_cast<float4*>(&sxs[row][4 * q]) =
            *reinterpret_cast<const float4*>(&bs[(size_t)row * CS + 4 * q]);
    }
    if (tid < CC) sss[tid] = ssum[(size_t)r * CC + tid];
    __syncthreads();

    // band scores: x1 = sxs[t][0..15], x2 = sxs[s][16..31]
    if (tid < TPC * 9) {
        int tpl = tid / 9, k = tid - tpl * 9;
        int t = 2 * (tp0 + tpl);
        int s = t - KH + k;
        float sc = 0.f;
        if (s >= 0 && s < TT) {
            const float4* x1 = reinterpret_cast<const float4*>(&sxs[t - s_lo][0]);
            const float4* x2 = reinterpret_cast<const float4*>(&sxs[s - s_lo][16]);
#pragma unroll
            for (int q = 0; q < 4; ++q) {
                float4 a = x1[q], b = x2[q];
                sc += a.x * b.x + a.y * b.y + a.z * b.z + a.w * b.w;
            }
        }
        sscore[tpl][k] = sc;
    }
    __syncthreads();

    // softmax coefficients (out-of-band zeros fold analytically)
    if (tid < TPC) {
        int tpl = tid;
        int t = 2 * (tp0 + tpl);
        float m = 0.f;
        int nb = 0;
#pragma unroll
        for (int k = 0; k < 9; ++k) {
            int s = t - KH + k;
            if (s >= 0 && s < TT) { nb++; m = fmaxf(m, sscore[tpl][k]); }
        }
        float wbg = __expf(-m);
        float Z = (float)(TT - nb) * wbg;
        float e[9];
#pragma unroll
        for (int k = 0; k < 9; ++k) {
            int s = t - KH + k;
            float ek = (s >= 0 && s < TT) ? __expf(sscore[tpl][k] - m) : 0.f;
            e[k] = ek;
            Z += ek;
        }
        float inv = 1.f / Z;
#pragma unroll
        for (int k = 0; k < 9; ++k) {
            int s = t - KH + k;
            scoef[tpl][k] = (s >= 0 && s < TT) ? (e[k] - wbg) * inv : 0.f;
        }
        scoef[tpl][9] = wbg * inv;
    }
    __syncthreads();

    // tmp[r][tp][c] = cbg*ssum[c] + sum_k coef_k * xwv_band[row][c]
    for (int i = tid; i < TPC * CC; i += 256) {
        int tpl = i >> 6, c = i & 63;
        int t = 2 * (tp0 + tpl);
        int row0 = t - KH - s_lo;
        float val = scoef[tpl][9] * sss[c];
#pragma unroll
        for (int k = 0; k < 9; ++k) {
            int row = row0 + k;
            row = min(max(row, 0), rows - 1);   // coef is 0 for invalid slots
            val += scoef[tpl][k] * sxv[row][c];
        }
        tmp[((size_t)r * TPOUT + (tp0 + tpl)) * CC + c] = val;
    }
}

// ---------------- Kernel 3: tmp[n][v][tp][c] -> out[n][c][tp][v] -------------
#define TPT 5
__global__ __launch_bounds__(256) void k3_transpose(const float* __restrict__ tmp,
                                                    float* __restrict__ out) {
    __shared__ float tile[VV][TPT][65];
    const int n = blockIdx.y;
    const int tp0 = blockIdx.x * TPT;
    const int tid = threadIdx.x;

    const float* src = tmp + (size_t)n * (VV * TPOUT * CC);
    for (int i = tid; i < VV * TPT * CC; i += 256) {
        int v = i / (TPT * CC);
        int rem = i - v * (TPT * CC);
        int tpl = rem >> 6, c = rem & 63;
        tile[v][tpl][c] = src[((size_t)v * TPOUT + tp0 + tpl) * CC + c];
    }
    __syncthreads();
    float* dst = out + (size_t)n * (CC * TPOUT * VV);
    for (int j = tid; j < CC * TPT * VV; j += 256) {
        int c = j / (TPT * VV);
        int rem = j - c * (TPT * VV);
        int tpl = rem / VV, v = rem - tpl * VV;
        dst[(size_t)c * (TPOUT * VV) + (tp0 + tpl) * VV + v] = tile[v][tpl][c];
    }
}

extern "C" void kernel_launch(void* const* d_in, const int* in_sizes, int n_in,
                              void* d_out, int out_size, void* d_ws, size_t ws_size,
                              hipStream_t stream) {
    const float* x     = (const float*)d_in[0];
    const float* W     = (const float*)d_in[1];
    const float* alpha = (const float*)d_in[2];
    const float* phi   = (const float*)d_in[3];
    float* out = (float*)d_out;

    float* xwv  = (float*)d_ws;                         // 800*300*64 = 15,360,000 f
    float* xws  = xwv + (size_t)800 * 300 * CC;         // 800*300*32 =  7,680,000 f
    float* tmp  = xws + (size_t)800 * 300 * CS;         // 800*150*64 =  7,680,000 f
    float* ssum = tmp + (size_t)800 * 150 * 64;         // 800*64     =     51,200 f
    float* Ws   = ssum + (size_t)800 * 64;              // 64*32      =      2,048 f
                                                        // total ~123 MB

    k0_ws<<<1, 256, 0, stream>>>(W, alpha, phi, Ws);
    dim3 g1(TT / TC, NB);
    k1_xw<<<g1, 256, 0, stream>>>(x, W, Ws, xwv, xws);
    k1b_colsum<<<NB * VV, 256, 0, stream>>>(xwv, ssum);
    dim3 g2(NCHUNK, NB * VV);
    k2_attn<<<g2, 256, 0, stream>>>(xwv, xws, ssum, tmp);
    dim3 g3(TPOUT / TPT, NB);
    k3_transpose<<<g3, 256, 0, stream>>>(tmp, out);
}

// Round 8
// 108.623 us; speedup vs baseline: 1.1645x; 1.0856x over previous
//
#include <hip/hip_runtime.h>

#define NB 32
#define CC 64
#define CS 32      // score cols: 0..15 alpha(x1), 16..31 phi(x2)
#define TT 300
#define VV 25
#define HH 16
#define TPOUT 150
#define KH 4       // kernel//2
#define TC 4       // timesteps per k1 block

#define TPC 25     // selected rows per k2 chunk
#define NCHUNK 6
#define ROWS_MAX 57
#define SLV 68     // k2 value-band LDS leading dim
#define SLS 36     // k2 score-band LDS leading dim

#define ALD 140    // sA row stride (elems): 70 dw -> 8-row stride = 560 dw = 16 mod 32 (2-way, free)
#define BLD 108    // sB row stride (elems): 54 dw -> 8-row stride = 432 dw = 16 mod 32 (2-way, free)

typedef __attribute__((ext_vector_type(4))) float f32x4;
typedef __attribute__((ext_vector_type(8))) short bf16x8;

static __device__ __forceinline__ unsigned short f2bf(float f) {
    unsigned u = __float_as_uint(f);
    unsigned r = (u + 0x7FFFu + ((u >> 16) & 1u)) >> 16;   // RNE
    return (unsigned short)r;
}
static __device__ __forceinline__ float bf2f(unsigned short h) {
    return __uint_as_float(((unsigned)h) << 16);
}

// ---------------- Kernel 0: Wext = [W | W@aT | W@pT] -> split bf16 h/l -------
__global__ __launch_bounds__(256) void k0_prep(const float* __restrict__ W,
                                               const float* __restrict__ alpha,
                                               const float* __restrict__ phi,
                                               unsigned short* __restrict__ Wh,
                                               unsigned short* __restrict__ Wl) {
    __shared__ float sW[64][64];
    __shared__ float sA[32][64];   // rows 0..15 alpha, 16..31 phi
    __shared__ float sWe[64][96];
    const int tid = threadIdx.x;
    for (int i = tid; i < 1024; i += 256)
        reinterpret_cast<float4*>(&sW[0][0])[i] = reinterpret_cast<const float4*>(W)[i];
    for (int i = tid; i < 512; i += 256) {
        float4 v = (i < 256) ? reinterpret_cast<const float4*>(alpha)[i]
                             : reinterpret_cast<const float4*>(phi)[i - 256];
        reinterpret_cast<float4*>(&sA[0][0])[i] = v;
    }
    __syncthreads();
    for (int i = tid; i < 1024; i += 256) {           // copy W -> cols 0..63
        int ci = i >> 4, q = i & 15;
        *reinterpret_cast<float4*>(&sWe[ci][4 * q]) =
            reinterpret_cast<const float4*>(&sW[ci][0])[q];
    }
    for (int i = tid; i < 2048; i += 256) {           // dots -> cols 64..95
        int ci = i >> 5, j = i & 31;
        const float4* a = reinterpret_cast<const float4*>(&sW[ci][0]);
        const float4* b = reinterpret_cast<const float4*>(&sA[j][0]);
        float acc = 0.f;
#pragma unroll
        for (int q = 0; q < 16; ++q) {
            float4 u = a[q], w = b[q];
            acc += u.x * w.x + u.y * w.y + u.z * w.z + u.w * w.w;
        }
        sWe[ci][64 + j] = acc;
    }
    __syncthreads();
    for (int i = tid; i < 6144; i += 256) {           // split: plain [k][96] layout
        int k = i / 96, c = i - 96 * k;
        float f = sWe[k][c];
        unsigned short h = f2bf(f);
        Wh[i] = h;
        Wl[i] = f2bf(f - bf2f(h));
    }
}

// ---------------- Kernel 1: xwv/xws via bf16 MFMA with h/l split -------------
// A = x-slice (M=100 pad 128, K=64) split to bf16 h/l; B = Wext (K=64, N=96).
// Value cols (nt<4): 1 pass (h*h).  Score cols (nt 4,5): 3 passes (hh+hl+lh).
__global__ __launch_bounds__(256) void k1_mfma(const float* __restrict__ x,
                                               const unsigned short* __restrict__ Wh,
                                               const unsigned short* __restrict__ Wl,
                                               float* __restrict__ xwv,
                                               float* __restrict__ xws) {
    __shared__ __align__(16) unsigned short sAh[64][ALD], sAl[64][ALD];
    __shared__ __align__(16) unsigned short sBh[64][BLD], sBl[64][BLD];
    const int n  = blockIdx.y;
    const int t0 = blockIdx.x * TC;
    const int tid = threadIdx.x;

    // stage B (uint2 = 4 bf16; 96 elems = 24 chunks per row)
    for (int i = tid; i < 1536; i += 256) {
        int k = i / 24, ch = i - 24 * k;
        *reinterpret_cast<uint2*>(&sBh[k][4 * ch]) = reinterpret_cast<const uint2*>(Wh)[i];
        *reinterpret_cast<uint2*>(&sBl[k][4 * ch]) = reinterpret_cast<const uint2*>(Wl)[i];
    }
    // stage A: read x float4 (tv-contiguous), split to h/l, write ushort4
    const float* xb = x + (size_t)n * CC * TT * VV + (size_t)t0 * VV;
    for (int i = tid; i < 1600; i += 256) {
        int ci = i / 25, q = i - 25 * ci;
        float4 v = *reinterpret_cast<const float4*>(&xb[(size_t)ci * TT * VV + 4 * q]);
        unsigned short h0 = f2bf(v.x), h1 = f2bf(v.y), h2 = f2bf(v.z), h3 = f2bf(v.w);
        ushort4 hv = {h0, h1, h2, h3};
        ushort4 lv = {f2bf(v.x - bf2f(h0)), f2bf(v.y - bf2f(h1)),
                      f2bf(v.z - bf2f(h2)), f2bf(v.w - bf2f(h3))};
        *reinterpret_cast<ushort4*>(&sAh[ci][4 * q]) = hv;
        *reinterpret_cast<ushort4*>(&sAl[ci][4 * q]) = lv;
    }
    __syncthreads();

    const int w    = tid >> 6;
    const int lane = tid & 63;
    const int lm   = lane & 15;
    const int g    = lane >> 4;

    f32x4 acc[2][6];
#pragma unroll
    for (int a = 0; a < 2; ++a)
#pragma unroll
        for (int b = 0; b < 6; ++b) acc[a][b] = (f32x4){0.f, 0.f, 0.f, 0.f};

#pragma unroll
    for (int kh = 0; kh < 2; ++kh) {
        const int kb = kh * 32 + g * 8;
        // A fragments: lane holds A[m = mt*16+lm][k = kb..kb+7]
        bf16x8 ah[2], al[2];
#pragma unroll
        for (int mti = 0; mti < 2; ++mti) {
            const int mc = (2 * w + mti) * 16 + lm;
#pragma unroll
            for (int j = 0; j < 8; ++j) {
                ah[mti][j] = (short)sAh[kb + j][mc];
                al[mti][j] = (short)sAl[kb + j][mc];
            }
        }
#pragma unroll
        for (int nt = 0; nt < 6; ++nt) {
            const int nc = nt * 16 + lm;
            bf16x8 bh;
#pragma unroll
            for (int j = 0; j < 8; ++j) bh[j] = (short)sBh[kb + j][nc];
            acc[0][nt] = __builtin_amdgcn_mfma_f32_16x16x32_bf16(ah[0], bh, acc[0][nt], 0, 0, 0);
            acc[1][nt] = __builtin_amdgcn_mfma_f32_16x16x32_bf16(ah[1], bh, acc[1][nt], 0, 0, 0);
            if (nt >= 4) {   // score cols: add h*l + l*h correction passes
                bf16x8 bl;
#pragma unroll
                for (int j = 0; j < 8; ++j) bl[j] = (short)sBl[kb + j][nc];
                acc[0][nt] = __builtin_amdgcn_mfma_f32_16x16x32_bf16(ah[0], bl, acc[0][nt], 0, 0, 0);
                acc[1][nt] = __builtin_amdgcn_mfma_f32_16x16x32_bf16(ah[1], bl, acc[1][nt], 0, 0, 0);
                acc[0][nt] = __builtin_amdgcn_mfma_f32_16x16x32_bf16(al[0], bh, acc[0][nt], 0, 0, 0);
                acc[1][nt] = __builtin_amdgcn_mfma_f32_16x16x32_bf16(al[1], bh, acc[1][nt], 0, 0, 0);
            }
        }
    }

    // epilogue: D lane l reg j -> row = mt*16 + g*4 + j, col = nt*16 + lm
#pragma unroll
    for (int mti = 0; mti < 2; ++mti) {
        const int mt = 2 * w + mti;
#pragma unroll
        for (int j = 0; j < 4; ++j) {
            const int tv = mt * 16 + g * 4 + j;
            if (tv < 100) {
                int tloc = tv / 25, vv = tv - 25 * tloc;
                size_t row = (size_t)(n * VV + vv) * TT + (t0 + tloc);
#pragma unroll
                for (int nt = 0; nt < 6; ++nt) {
                    float val = acc[mti][nt][j];
                    if (nt < 4) xwv[row * CC + nt * 16 + lm] = val;
                    else        xws[row * CS + (nt - 4) * 16 + lm] = val;
                }
            }
        }
    }
}

// ---------------- Kernel 1b: ssum[r][c] = sum_t xwv[r][t][c] -----------------
__global__ __launch_bounds__(256) void k1b_colsum(const float* __restrict__ xwv,
                                                  float* __restrict__ ssum) {
    __shared__ float sred[16][64];
    const int r = blockIdx.x;
    const float* p = xwv + (size_t)r * TT * CC;
    const int c4 = threadIdx.x & 15, g = threadIdx.x >> 4;
    float4 a = {0.f, 0.f, 0.f, 0.f};
    for (int t = g; t < TT; t += 16) {
        float4 v = *reinterpret_cast<const float4*>(&p[(size_t)t * CC + 4 * c4]);
        a.x += v.x; a.y += v.y; a.z += v.z; a.w += v.w;
    }
    *reinterpret_cast<float4*>(&sred[g][4 * c4]) = a;
    __syncthreads();
    if (threadIdx.x < 64) {
        float acc = 0.f;
#pragma unroll
        for (int g2 = 0; g2 < 16; ++g2) acc += sred[g2][threadIdx.x];
        ssum[(size_t)r * CC + threadIdx.x] = acc;
    }
}

// ---------------- Kernel 2: banded attention, one (chunk, r) per block -------
__global__ __launch_bounds__(256) void k2_attn(const float* __restrict__ xwv,
                                               const float* __restrict__ xws,
                                               const float* __restrict__ ssum,
                                               float* __restrict__ tmp) {
    const int ch = blockIdx.x;    // 0..5
    const int r  = blockIdx.y;    // n*25 + v

    __shared__ __align__(16) float sxv[ROWS_MAX][SLV];  // value cols
    __shared__ __align__(16) float sxs[ROWS_MAX][SLS];  // score cols
    __shared__ float sss[CC];
    __shared__ float sscore[TPC][9];
    __shared__ float scoef[TPC][10];

    const int tid = threadIdx.x;
    const int tp0 = ch * TPC;
    const int s_lo = max(0, 2 * tp0 - KH);
    const int s_hi = min(TT - 1, 2 * (tp0 + TPC - 1) + KH);
    const int rows = s_hi - s_lo + 1;

    const float* bv = xwv + ((size_t)r * TT + s_lo) * CC;
    for (int i = tid; i < rows * 16; i += 256) {
        int row = i >> 4, q = i & 15;
        *reinterpret_cast<float4*>(&sxv[row][4 * q]) =
            *reinterpret_cast<const float4*>(&bv[(size_t)row * CC + 4 * q]);
    }
    const float* bs = xws + ((size_t)r * TT + s_lo) * CS;
    for (int i = tid; i < rows * 8; i += 256) {
        int row = i >> 3, q = i & 7;
        *reinterpret_cast<float4*>(&sxs[row][4 * q]) =
            *reinterpret_cast<const float4*>(&bs[(size_t)row * CS + 4 * q]);
    }
    if (tid < CC) sss[tid] = ssum[(size_t)r * CC + tid];
    __syncthreads();

    // band scores: x1 = sxs[t][0..15], x2 = sxs[s][16..31]
    if (tid < TPC * 9) {
        int tpl = tid / 9, k = tid - tpl * 9;
        int t = 2 * (tp0 + tpl);
        int s = t - KH + k;
        float sc = 0.f;
        if (s >= 0 && s < TT) {
            const float4* x1 = reinterpret_cast<const float4*>(&sxs[t - s_lo][0]);
            const float4* x2 = reinterpret_cast<const float4*>(&sxs[s - s_lo][16]);
#pragma unroll
            for (int q = 0; q < 4; ++q) {
                float4 a = x1[q], b = x2[q];
                sc += a.x * b.x + a.y * b.y + a.z * b.z + a.w * b.w;
            }
        }
        sscore[tpl][k] = sc;
    }
    __syncthreads();

    // softmax coefficients (out-of-band zeros fold analytically)
    if (tid < TPC) {
        int tpl = tid;
        int t = 2 * (tp0 + tpl);
        float m = 0.f;
        int nb = 0;
#pragma unroll
        for (int k = 0; k < 9; ++k) {
            int s = t - KH + k;
            if (s >= 0 && s < TT) { nb++; m = fmaxf(m, sscore[tpl][k]); }
        }
        float wbg = __expf(-m);
        float Z = (float)(TT - nb) * wbg;
        float e[9];
#pragma unroll
        for (int k = 0; k < 9; ++k) {
            int s = t - KH + k;
            float ek = (s >= 0 && s < TT) ? __expf(sscore[tpl][k] - m) : 0.f;
            e[k] = ek;
            Z += ek;
        }
        float inv = 1.f / Z;
#pragma unroll
        for (int k = 0; k < 9; ++k) {
            int s = t - KH + k;
            scoef[tpl][k] = (s >= 0 && s < TT) ? (e[k] - wbg) * inv : 0.f;
        }
        scoef[tpl][9] = wbg * inv;
    }
    __syncthreads();

    // tmp[r][tp][c] = cbg*ssum[c] + sum_k coef_k * xwv_band[row][c]
    for (int i = tid; i < TPC * CC; i += 256) {
        int tpl = i >> 6, c = i & 63;
        int t = 2 * (tp0 + tpl);
        int row0 = t - KH - s_lo;
        float val = scoef[tpl][9] * sss[c];
#pragma unroll
        for (int k = 0; k < 9; ++k) {
            int row = row0 + k;
            row = min(max(row, 0), rows - 1);   // coef is 0 for invalid slots
            val += scoef[tpl][k] * sxv[row][c];
        }
        tmp[((size_t)r * TPOUT + (tp0 + tpl)) * CC + c] = val;
    }
}

// ---------------- Kernel 3: tmp[n][v][tp][c] -> out[n][c][tp][v] -------------
#define TPT 5
__global__ __launch_bounds__(256) void k3_transpose(const float* __restrict__ tmp,
                                                    float* __restrict__ out) {
    __shared__ float tile[VV][TPT][65];
    const int n = blockIdx.y;
    const int tp0 = blockIdx.x * TPT;
    const int tid = threadIdx.x;

    const float* src = tmp + (size_t)n * (VV * TPOUT * CC);
    for (int i = tid; i < VV * TPT * CC; i += 256) {
        int v = i / (TPT * CC);
        int rem = i - v * (TPT * CC);
        int tpl = rem >> 6, c = rem & 63;
        tile[v][tpl][c] = src[((size_t)v * TPOUT + tp0 + tpl) * CC + c];
    }
    __syncthreads();
    float* dst = out + (size_t)n * (CC * TPOUT * VV);
    for (int j = tid; j < CC * TPT * VV; j += 256) {
        int c = j / (TPT * VV);
        int rem = j - c * (TPT * VV);
        int tpl = rem / VV, v = rem - tpl * VV;
        dst[(size_t)c * (TPOUT * VV) + (tp0 + tpl) * VV + v] = tile[v][tpl][c];
    }
}

extern "C" void kernel_launch(void* const* d_in, const int* in_sizes, int n_in,
                              void* d_out, int out_size, void* d_ws, size_t ws_size,
                              hipStream_t stream) {
    const float* x     = (const float*)d_in[0];
    const float* W     = (const float*)d_in[1];
    const float* alpha = (const float*)d_in[2];
    const float* phi   = (const float*)d_in[3];
    float* out = (float*)d_out;

    float* xwv  = (float*)d_ws;                         // 800*300*64 = 15,360,000 f
    float* xws  = xwv + (size_t)800 * 300 * CC;         // 800*300*32 =  7,680,000 f
    float* tmp  = xws + (size_t)800 * 300 * CS;         // 800*150*64 =  7,680,000 f
    float* ssum = tmp + (size_t)800 * 150 * 64;         // 800*64     =     51,200 f
    unsigned short* Wh = (unsigned short*)(ssum + (size_t)800 * 64);   // 6144 us (16B-aligned)
    unsigned short* Wl = Wh + 6144;

    k0_prep<<<1, 256, 0, stream>>>(W, alpha, phi, Wh, Wl);
    dim3 g1(TT / TC, NB);
    k1_mfma<<<g1, 256, 0, stream>>>(x, Wh, Wl, xwv, xws);
    k1b_colsum<<<NB * VV, 256, 0, stream>>>(xwv, ssum);
    dim3 g2(NCHUNK, NB * VV);
    k2_attn<<<g2, 256, 0, stream>>>(xwv, xws, ssum, tmp);
    dim3 g3(TPOUT / TPT, NB);
    k3_transpose<<<g3, 256, 0, stream>>>(tmp, out);
}

// Round 9
// 97.759 us; speedup vs baseline: 1.2940x; 1.1111x over previous
//
#include <hip/hip_runtime.h>

#define NB 32
#define CC 64
#define CS 32      // score cols: 0..15 alpha(x1), 16..31 phi(x2)
#define TT 300
#define VV 25
#define HH 16
#define TPOUT 150
#define KH 4       // kernel//2
#define TC 4       // timesteps per k1 block

#define TPC 25     // selected rows per k2 chunk
#define NCHUNK 6
#define ROWS_MAX 57
#define SLV 68     // k2 value-band LDS leading dim
#define SLS 36     // k2 score-band LDS leading dim

#define ALD 72     // sA row stride in u16 (144 B: 16B-aligned, 36 dw = 4 mod 32 banks -> 2-way free reads)

typedef __attribute__((ext_vector_type(4))) float f32x4;
typedef __attribute__((ext_vector_type(8))) short bf16x8;

static __device__ __forceinline__ unsigned short f2bf(float f) {
    unsigned u = __float_as_uint(f);
    unsigned r = (u + 0x7FFFu + ((u >> 16) & 1u)) >> 16;   // RNE
    return (unsigned short)r;
}
static __device__ __forceinline__ float bf2f(unsigned short h) {
    return __uint_as_float(((unsigned)h) << 16);
}

// ------- Kernel 0: Wext = [W | W@aT | W@pT] -> bf16 h/l, FRAGMENT-MAJOR -----
// Output layout: Wfm[((k>>3)*96 + n)*8 + (k&7)] so a lane's B-fragment
// (8 consecutive k for one n) is one contiguous 16 B global load.
__global__ __launch_bounds__(256) void k0_prep(const float* __restrict__ W,
                                               const float* __restrict__ alpha,
                                               const float* __restrict__ phi,
                                               unsigned short* __restrict__ Wh,
                                               unsigned short* __restrict__ Wl) {
    __shared__ float sW[64][64];
    __shared__ float sA[32][64];   // rows 0..15 alpha, 16..31 phi
    __shared__ float sWe[64][96];
    const int tid = threadIdx.x;
    for (int i = tid; i < 1024; i += 256)
        reinterpret_cast<float4*>(&sW[0][0])[i] = reinterpret_cast<const float4*>(W)[i];
    for (int i = tid; i < 512; i += 256) {
        float4 v = (i < 256) ? reinterpret_cast<const float4*>(alpha)[i]
                             : reinterpret_cast<const float4*>(phi)[i - 256];
        reinterpret_cast<float4*>(&sA[0][0])[i] = v;
    }
    __syncthreads();
    for (int i = tid; i < 1024; i += 256) {           // copy W -> cols 0..63
        int ci = i >> 4, q = i & 15;
        *reinterpret_cast<float4*>(&sWe[ci][4 * q]) =
            reinterpret_cast<const float4*>(&sW[ci][0])[q];
    }
    for (int i = tid; i < 2048; i += 256) {           // dots -> cols 64..95
        int ci = i >> 5, j = i & 31;
        const float4* a = reinterpret_cast<const float4*>(&sW[ci][0]);
        const float4* b = reinterpret_cast<const float4*>(&sA[j][0]);
        float acc = 0.f;
#pragma unroll
        for (int q = 0; q < 16; ++q) {
            float4 u = a[q], w = b[q];
            acc += u.x * w.x + u.y * w.y + u.z * w.z + u.w * w.w;
        }
        sWe[ci][64 + j] = acc;
    }
    __syncthreads();
    for (int i = tid; i < 6144; i += 256) {
        int k = i / 96, c = i - 96 * k;
        float f = sWe[k][c];
        unsigned short h = f2bf(f);
        int off = (((k >> 3) * 96) + c) * 8 + (k & 7);
        Wh[off] = h;
        Wl[off] = f2bf(f - bf2f(h));
    }
}

// ------- Kernel 1: xwv/xws via bf16 MFMA, b128 fragments, B from global -----
// A staged [m][k] (fragment-major): 1 ds_read_b128 per A-fragment.
// B fragments: 16 B global loads from the 24 KB L1-resident Wh/Wl tables.
// Value cols (nt<4): 1 pass (hh). Score cols (nt 4,5): 3 passes (hh+hl+lh).
__global__ __launch_bounds__(256, 4) void k1_mfma(const float* __restrict__ x,
                                                  const unsigned short* __restrict__ Bh,
                                                  const unsigned short* __restrict__ Bl,
                                                  float* __restrict__ xwv,
                                                  float* __restrict__ xws) {
    __shared__ __align__(16) unsigned short sAh[128][ALD];
    __shared__ __align__(16) unsigned short sAl[128][ALD];
    const int n  = blockIdx.y;
    const int t0 = blockIdx.x * TC;
    const int tid = threadIdx.x;

    // ---- stage A: thread (cig, tvq) loads 8 ci x 4 tv, packs, writes b128 ----
    if (tid < 200) {
        const int cig = tid / 25, tvq = tid % 25;
        const float* xp = x + (size_t)n * CC * TT * VV + (size_t)t0 * VV + 4 * tvq;
        unsigned short mh[4][8], ml[4][8];
#pragma unroll
        for (int u = 0; u < 8; ++u) {
            const int ci = cig * 8 + u;
            float4 v = *reinterpret_cast<const float4*>(&xp[(size_t)ci * TT * VV]);
            unsigned short h0 = f2bf(v.x), h1 = f2bf(v.y), h2 = f2bf(v.z), h3 = f2bf(v.w);
            mh[0][u] = h0; mh[1][u] = h1; mh[2][u] = h2; mh[3][u] = h3;
            ml[0][u] = f2bf(v.x - bf2f(h0));
            ml[1][u] = f2bf(v.y - bf2f(h1));
            ml[2][u] = f2bf(v.z - bf2f(h2));
            ml[3][u] = f2bf(v.w - bf2f(h3));
        }
#pragma unroll
        for (int i = 0; i < 4; ++i) {
            *reinterpret_cast<uint4*>(&sAh[4 * tvq + i][cig * 8]) =
                *reinterpret_cast<const uint4*>(&mh[i][0]);
            *reinterpret_cast<uint4*>(&sAl[4 * tvq + i][cig * 8]) =
                *reinterpret_cast<const uint4*>(&ml[i][0]);
        }
    }
    __syncthreads();

    const int w    = tid >> 6;
    const int lane = tid & 63;
    const int lm   = lane & 15;
    const int g    = lane >> 4;

    f32x4 acc[2][6];
#pragma unroll
    for (int a = 0; a < 2; ++a)
#pragma unroll
        for (int b = 0; b < 6; ++b) acc[a][b] = (f32x4){0.f, 0.f, 0.f, 0.f};

#pragma unroll
    for (int kh = 0; kh < 2; ++kh) {
        const int kb = kh * 32 + g * 8;
        const int kc = kb >> 3;
        const int mc0 = (2 * w + 0) * 16 + lm;
        const int mc1 = (2 * w + 1) * 16 + lm;
        bf16x8 ah0 = *reinterpret_cast<const bf16x8*>(&sAh[mc0][kb]);
        bf16x8 ah1 = *reinterpret_cast<const bf16x8*>(&sAh[mc1][kb]);
        bf16x8 al0 = *reinterpret_cast<const bf16x8*>(&sAl[mc0][kb]);
        bf16x8 al1 = *reinterpret_cast<const bf16x8*>(&sAl[mc1][kb]);
#pragma unroll
        for (int nt = 0; nt < 6; ++nt) {
            const int nc = nt * 16 + lm;
            bf16x8 bh = *reinterpret_cast<const bf16x8*>(&Bh[(size_t)(kc * 96 + nc) * 8]);
            acc[0][nt] = __builtin_amdgcn_mfma_f32_16x16x32_bf16(ah0, bh, acc[0][nt], 0, 0, 0);
            acc[1][nt] = __builtin_amdgcn_mfma_f32_16x16x32_bf16(ah1, bh, acc[1][nt], 0, 0, 0);
            if (nt >= 4) {   // score cols: h*l + l*h correction passes
                bf16x8 bl = *reinterpret_cast<const bf16x8*>(&Bl[(size_t)(kc * 96 + nc) * 8]);
                acc[0][nt] = __builtin_amdgcn_mfma_f32_16x16x32_bf16(ah0, bl, acc[0][nt], 0, 0, 0);
                acc[1][nt] = __builtin_amdgcn_mfma_f32_16x16x32_bf16(ah1, bl, acc[1][nt], 0, 0, 0);
                acc[0][nt] = __builtin_amdgcn_mfma_f32_16x16x32_bf16(al0, bh, acc[0][nt], 0, 0, 0);
                acc[1][nt] = __builtin_amdgcn_mfma_f32_16x16x32_bf16(al1, bh, acc[1][nt], 0, 0, 0);
            }
        }
    }

    // epilogue: D lane reg j -> row = mt*16 + g*4 + j, col = nt*16 + lm
#pragma unroll
    for (int mti = 0; mti < 2; ++mti) {
        const int mt = 2 * w + mti;
#pragma unroll
        for (int j = 0; j < 4; ++j) {
            const int tv = mt * 16 + g * 4 + j;
            if (tv < 100) {
                int tloc = tv / 25, vv = tv - 25 * tloc;
                size_t row = (size_t)(n * VV + vv) * TT + (t0 + tloc);
#pragma unroll
                for (int nt = 0; nt < 6; ++nt) {
                    float val = acc[mti][nt][j];
                    if (nt < 4) xwv[row * CC + nt * 16 + lm] = val;
                    else        xws[row * CS + (nt - 4) * 16 + lm] = val;
                }
            }
        }
    }
}

// ---------------- Kernel 1b: ssum[r][c] = sum_t xwv[r][t][c] -----------------
__global__ __launch_bounds__(256) void k1b_colsum(const float* __restrict__ xwv,
                                                  float* __restrict__ ssum) {
    __shared__ float sred[16][64];
    const int r = blockIdx.x;
    const float* p = xwv + (size_t)r * TT * CC;
    const int c4 = threadIdx.x & 15, g = threadIdx.x >> 4;
    float4 a = {0.f, 0.f, 0.f, 0.f};
    for (int t = g; t < TT; t += 16) {
        float4 v = *reinterpret_cast<const float4*>(&p[(size_t)t * CC + 4 * c4]);
        a.x += v.x; a.y += v.y; a.z += v.z; a.w += v.w;
    }
    *reinterpret_cast<float4*>(&sred[g][4 * c4]) = a;
    __syncthreads();
    if (threadIdx.x < 64) {
        float acc = 0.f;
#pragma unroll
        for (int g2 = 0; g2 < 16; ++g2) acc += sred[g2][threadIdx.x];
        ssum[(size_t)r * CC + threadIdx.x] = acc;
    }
}

// ---------------- Kernel 2: banded attention, one (chunk, r) per block -------
__global__ __launch_bounds__(256) void k2_attn(const float* __restrict__ xwv,
                                               const float* __restrict__ xws,
                                               const float* __restrict__ ssum,
                                               float* __restrict__ tmp) {
    const int ch = blockIdx.x;    // 0..5
    const int r  = blockIdx.y;    // n*25 + v

    __shared__ __align__(16) float sxv[ROWS_MAX][SLV];  // value cols
    __shared__ __align__(16) float sxs[ROWS_MAX][SLS];  // score cols
    __shared__ float sss[CC];
    __shared__ float sscore[TPC][9];
    __shared__ float scoef[TPC][10];

    const int tid = threadIdx.x;
    const int tp0 = ch * TPC;
    const int s_lo = max(0, 2 * tp0 - KH);
    const int s_hi = min(TT - 1, 2 * (tp0 + TPC - 1) + KH);
    const int rows = s_hi - s_lo + 1;

    const float* bv = xwv + ((size_t)r * TT + s_lo) * CC;
    for (int i = tid; i < rows * 16; i += 256) {
        int row = i >> 4, q = i & 15;
        *reinterpret_cast<float4*>(&sxv[row][4 * q]) =
            *reinterpret_cast<const float4*>(&bv[(size_t)row * CC + 4 * q]);
    }
    const float* bs = xws + ((size_t)r * TT + s_lo) * CS;
    for (int i = tid; i < rows * 8; i += 256) {
        int row = i >> 3, q = i & 7;
        *reinterpret_cast<float4*>(&sxs[row][4 * q]) =
            *reinterpret_cast<const float4*>(&bs[(size_t)row * CS + 4 * q]);
    }
    if (tid < CC) sss[tid] = ssum[(size_t)r * CC + tid];
    __syncthreads();

    // band scores: x1 = sxs[t][0..15], x2 = sxs[s][16..31]
    if (tid < TPC * 9) {
        int tpl = tid / 9, k = tid - tpl * 9;
        int t = 2 * (tp0 + tpl);
        int s = t - KH + k;
        float sc = 0.f;
        if (s >= 0 && s < TT) {
            const float4* x1 = reinterpret_cast<const float4*>(&sxs[t - s_lo][0]);
            const float4* x2 = reinterpret_cast<const float4*>(&sxs[s - s_lo][16]);
#pragma unroll
            for (int q = 0; q < 4; ++q) {
                float4 a = x1[q], b = x2[q];
                sc += a.x * b.x + a.y * b.y + a.z * b.z + a.w * b.w;
            }
        }
        sscore[tpl][k] = sc;
    }
    __syncthreads();

    // softmax coefficients (out-of-band zeros fold analytically)
    if (tid < TPC) {
        int tpl = tid;
        int t = 2 * (tp0 + tpl);
        float m = 0.f;
        int nb = 0;
#pragma unroll
        for (int k = 0; k < 9; ++k) {
            int s = t - KH + k;
            if (s >= 0 && s < TT) { nb++; m = fmaxf(m, sscore[tpl][k]); }
        }
        float wbg = __expf(-m);
        float Z = (float)(TT - nb) * wbg;
        float e[9];
#pragma unroll
        for (int k = 0; k < 9; ++k) {
            int s = t - KH + k;
            float ek = (s >= 0 && s < TT) ? __expf(sscore[tpl][k] - m) : 0.f;
            e[k] = ek;
            Z += ek;
        }
        float inv = 1.f / Z;
#pragma unroll
        for (int k = 0; k < 9; ++k) {
            int s = t - KH + k;
            scoef[tpl][k] = (s >= 0 && s < TT) ? (e[k] - wbg) * inv : 0.f;
        }
        scoef[tpl][9] = wbg * inv;
    }
    __syncthreads();

    // tmp[r][tp][c] = cbg*ssum[c] + sum_k coef_k * xwv_band[row][c]
    for (int i = tid; i < TPC * CC; i += 256) {
        int tpl = i >> 6, c = i & 63;
        int t = 2 * (tp0 + tpl);
        int row0 = t - KH - s_lo;
        float val = scoef[tpl][9] * sss[c];
#pragma unroll
        for (int k = 0; k < 9; ++k) {
            int row = row0 + k;
            row = min(max(row, 0), rows - 1);   // coef is 0 for invalid slots
            val += scoef[tpl][k] * sxv[row][c];
        }
        tmp[((size_t)r * TPOUT + (tp0 + tpl)) * CC + c] = val;
    }
}

// ---------------- Kernel 3: tmp[n][v][tp][c] -> out[n][c][tp][v] -------------
#define TPT 5
__global__ __launch_bounds__(256) void k3_transpose(const float* __restrict__ tmp,
                                                    float* __restrict__ out) {
    __shared__ float tile[VV][TPT][65];
    const int n = blockIdx.y;
    const int tp0 = blockIdx.x * TPT;
    const int tid = threadIdx.x;

    const float* src = tmp + (size_t)n * (VV * TPOUT * CC);
    for (int i = tid; i < VV * TPT * CC; i += 256) {
        int v = i / (TPT * CC);
        int rem = i - v * (TPT * CC);
        int tpl = rem >> 6, c = rem & 63;
        tile[v][tpl][c] = src[((size_t)v * TPOUT + tp0 + tpl) * CC + c];
    }
    __syncthreads();
    float* dst = out + (size_t)n * (CC * TPOUT * VV);
    for (int j = tid; j < CC * TPT * VV; j += 256) {
        int c = j / (TPT * VV);
        int rem = j - c * (TPT * VV);
        int tpl = rem / VV, v = rem - tpl * VV;
        dst[(size_t)c * (TPOUT * VV) + (tp0 + tpl) * VV + v] = tile[v][tpl][c];
    }
}

extern "C" void kernel_launch(void* const* d_in, const int* in_sizes, int n_in,
                              void* d_out, int out_size, void* d_ws, size_t ws_size,
                              hipStream_t stream) {
    const float* x     = (const float*)d_in[0];
    const float* W     = (const float*)d_in[1];
    const float* alpha = (const float*)d_in[2];
    const float* phi   = (const float*)d_in[3];
    float* out = (float*)d_out;

    float* xwv  = (float*)d_ws;                         // 800*300*64 = 15,360,000 f
    float* xws  = xwv + (size_t)800 * 300 * CC;         // 800*300*32 =  7,680,000 f
    float* tmp  = xws + (size_t)800 * 300 * CS;         // 800*150*64 =  7,680,000 f
    float* ssum = tmp + (size_t)800 * 150 * 64;         // 800*64     =     51,200 f
    unsigned short* Wh = (unsigned short*)(ssum + (size_t)800 * 64);   // 6144 u16, 16B-aligned
    unsigned short* Wl = Wh + 6144;

    k0_prep<<<1, 256, 0, stream>>>(W, alpha, phi, Wh, Wl);
    dim3 g1(TT / TC, NB);
    k1_mfma<<<g1, 256, 0, stream>>>(x, Wh, Wl, xwv, xws);
    k1b_colsum<<<NB * VV, 256, 0, stream>>>(xwv, ssum);
    dim3 g2(NCHUNK, NB * VV);
    k2_attn<<<g2, 256, 0, stream>>>(xwv, xws, ssum, tmp);
    dim3 g3(TPOUT / TPT, NB);
    k3_transpose<<<g3, 256, 0, stream>>>(tmp, out);
}